// Round 1
// baseline (610.194 us; speedup 1.0000x reference)
//
#include <hip/hip_runtime.h>
#include <hip/hip_bf16.h>
#include <math.h>

#define NTOK 4096   // B*S
#define DDIM 1024
#define HDIM 4096
#define EEXP 8

typedef __attribute__((ext_vector_type(8))) short short8;
typedef __attribute__((ext_vector_type(4))) float f32x4;

static __device__ __forceinline__ unsigned short f2bf(float f){
  unsigned int u = __float_as_uint(f);
  u += 0x7FFFu + ((u >> 16) & 1u);
  return (unsigned short)(u >> 16);
}

// ---------------- x -> bf16 ----------------
__global__ __launch_bounds__(256) void convert_x_kernel(const float* __restrict__ x,
                                                        short* __restrict__ xb){
  int i = blockIdx.x * blockDim.x + threadIdx.x;     // 524288 threads, 8 elems each
  const f32x4* src = (const f32x4*)x + (size_t)i * 2;
  f32x4 a = src[0], b = src[1];
  short8 o;
#pragma unroll
  for (int j = 0; j < 4; ++j){ o[j] = (short)f2bf(a[j]); o[j+4] = (short)f2bf(b[j]); }
  ((short8*)xb)[i] = o;
}

// ---------------- gate: logits, top-2, softmax ----------------
__global__ __launch_bounds__(64) void gate_kernel(const float* __restrict__ x,
    const float* __restrict__ gw, const float* __restrict__ gb,
    float* __restrict__ outF, int2* __restrict__ te, float2* __restrict__ tw,
    int* __restrict__ cnt){
  const int t = blockIdx.x;
  const int l = threadIdx.x;
  const f32x4* xr = (const f32x4*)(x + (size_t)t * DDIM);
  float acc[EEXP];
#pragma unroll
  for (int e = 0; e < EEXP; ++e) acc[e] = 0.f;
#pragma unroll
  for (int j = 0; j < 4; ++j){
    f32x4 xv = xr[l + 64*j];
#pragma unroll
    for (int e = 0; e < EEXP; ++e){
      f32x4 gv = ((const f32x4*)(gw + (size_t)e*DDIM))[l + 64*j];
      acc[e] += xv[0]*gv[0] + xv[1]*gv[1] + xv[2]*gv[2] + xv[3]*gv[3];
    }
  }
#pragma unroll
  for (int e = 0; e < EEXP; ++e){
#pragma unroll
    for (int off = 32; off > 0; off >>= 1) acc[e] += __shfl_xor(acc[e], off);
  }
  if (l == 0){
    float lg[EEXP];
#pragma unroll
    for (int e = 0; e < EEXP; ++e) lg[e] = acc[e] + gb[e];
    int e0 = 0; float v0 = lg[0];
#pragma unroll
    for (int e = 1; e < EEXP; ++e) if (lg[e] > v0){ v0 = lg[e]; e0 = e; }
    int e1 = -1; float v1 = -1e30f;
#pragma unroll
    for (int e = 0; e < EEXP; ++e) if (e != e0 && lg[e] > v1){ v1 = lg[e]; e1 = e; }
    float r  = expf(v1 - v0);
    float w0 = 1.f / (1.f + r);
    float w1 = r  / (1.f + r);
    outF[(size_t)NTOK*DDIM + 2*t    ] = (float)e0;   // selected, return order
    outF[(size_t)NTOK*DDIM + 2*t + 1] = (float)e1;
    te[t] = make_int2(e0, e1);
    tw[t] = make_float2(w0, w1);
    atomicAdd(&cnt[e0], 1);
    atomicAdd(&cnt[e1], 1);
  }
}

__global__ void scan_kernel(const int* __restrict__ cnt, int* __restrict__ offs){
  if (threadIdx.x == 0){
    int s = 0;
    for (int e = 0; e < EEXP; ++e){ offs[e] = s; s += cnt[e]; }
  }
}

__global__ __launch_bounds__(256) void scatter_kernel(const int2* __restrict__ te,
    const float2* __restrict__ tw, const int* __restrict__ offs,
    int* __restrict__ cur, int* __restrict__ tokp, float* __restrict__ wtp){
  int t = blockIdx.x * blockDim.x + threadIdx.x;
  if (t >= NTOK) return;
  int2 e = te[t]; float2 w = tw[t];
  int p0 = offs[e.x] + atomicAdd(&cur[e.x], 1);
  tokp[p0] = t; wtp[p0] = w.x;
  int p1 = offs[e.y] + atomicAdd(&cur[e.y], 1);
  tokp[p1] = t; wtp[p1] = w.y;
}

// out[t,:] = w0*b2[e0,:] + w1*b2[e1,:]  (bias pre-fold; GEMM2 atomically adds the rest)
__global__ __launch_bounds__(256) void out_init_kernel(const int2* __restrict__ te,
    const float2* __restrict__ tw, const float* __restrict__ b2, float* __restrict__ outF){
  const int t = blockIdx.x;
  int2 e = te[t]; float2 w = tw[t];
  const float* r0 = b2 + (size_t)e.x * DDIM;
  const float* r1 = b2 + (size_t)e.y * DDIM;
  for (int d = threadIdx.x; d < DDIM; d += 256)
    outF[(size_t)t * DDIM + d] = w.x * r0[d] + w.y * r1[d];
}

// ---------------- grouped GEMM ----------------
// PHASE 1: h = GELU(gather(xb) @ w1^T + b1)   M=cnt[e], N=HDIM, K=DDIM
// PHASE 2: out += wt * (h @ w2^T)             M=cnt[e], N=DDIM, K=HDIM
#define BM 128
#define BN 128
#define BK 64

template<int PHASE, int KDIM, int NDIM>
__global__ __launch_bounds__(256, 2) void moe_gemm(
    const short* __restrict__ Abase, const float* __restrict__ W,
    const float* __restrict__ bias,
    const int* __restrict__ cnts, const int* __restrict__ offs,
    const int* __restrict__ tokp, const float* __restrict__ wtp,
    short* __restrict__ Hout, float* __restrict__ Out){
  const int e   = blockIdx.z;
  const int cnt = cnts[e];
  const int m0  = blockIdx.y * BM;
  if (m0 >= cnt) return;
  const int off   = offs[e];
  const int mrows = min(BM, cnt - m0);
  const int n0    = blockIdx.x * BN;

  __shared__ short As[2][BM * BK];
  __shared__ short Bs[2][BM * BK];

  const int tid  = threadIdx.x;
  const int lane = tid & 63;
  const int wid  = tid >> 6;
  const int wr   = wid >> 1;   // wave row (0..1) -> 64 rows
  const int wc   = wid & 1;    // wave col (0..1) -> 64 cols

  // staging geometry: 256 threads * 16B = 4KB per pass; 4 passes per 16KB tile
  const int sr = tid >> 3;          // row 0..31 per pass
  const int sc = (tid & 7) * 8;     // element col (bf16) step 8

  size_t aRow[4];
#pragma unroll
  for (int it = 0; it < 4; ++it){
    int r  = sr + it * 32;
    int rr = min(r, mrows - 1);
    size_t g;
    if (PHASE == 1) g = (size_t)tokp[off + m0 + rr];
    else            g = (size_t)(off + m0 + rr);
    aRow[it] = g * KDIM + sc;
  }
  const float* wB = W + (size_t)e * NDIM * KDIM;
  size_t bRow[4];
#pragma unroll
  for (int it = 0; it < 4; ++it)
    bRow[it] = (size_t)(n0 + sr + it * 32) * KDIM + sc;

  int wOff[4];   // swizzled LDS offset (shorts)
#pragma unroll
  for (int it = 0; it < 4; ++it){
    int r  = sr + it * 32;
    int bc = (tid & 7) * 16;                       // byte col within 128B row
    wOff[it] = r * BK + ((bc ^ ((r & 7) << 4)) >> 1);
  }

  f32x4 acc[4][4];
#pragma unroll
  for (int i = 0; i < 4; ++i)
#pragma unroll
    for (int j = 0; j < 4; ++j) acc[i][j] = (f32x4){0.f, 0.f, 0.f, 0.f};

  short8 aR[4]; f32x4 bRa[4], bRb[4];

  auto LOADS = [&](int t){
    const int k0 = t * BK;
#pragma unroll
    for (int it = 0; it < 4; ++it)
      aR[it] = *(const short8*)(Abase + aRow[it] + k0);
#pragma unroll
    for (int it = 0; it < 4; ++it){
      const float* s = wB + bRow[it] + k0;
      bRa[it] = *(const f32x4*)s;
      bRb[it] = *(const f32x4*)(s + 4);
    }
  };
  auto DSWRITE = [&](int buf){
#pragma unroll
    for (int it = 0; it < 4; ++it){
      *(short8*)&As[buf][wOff[it]] = aR[it];
      short8 v;
#pragma unroll
      for (int j = 0; j < 4; ++j){
        v[j]     = (short)f2bf(bRa[it][j]);
        v[j + 4] = (short)f2bf(bRb[it][j]);
      }
      *(short8*)&Bs[buf][wOff[it]] = v;
    }
  };
  auto COMPUTE = [&](int buf){
#pragma unroll
    for (int kk = 0; kk < 2; ++kk){
      short8 af[4], bf[4];
      const int bc = kk * 64 + (lane >> 4) * 16;
#pragma unroll
      for (int i = 0; i < 4; ++i){
        int rA = wr * 64 + i * 16 + (lane & 15);
        af[i] = *(const short8*)&As[buf][rA * BK + ((bc ^ ((rA & 7) << 4)) >> 1)];
        int rB = wc * 64 + i * 16 + (lane & 15);
        bf[i] = *(const short8*)&Bs[buf][rB * BK + ((bc ^ ((rB & 7) << 4)) >> 1)];
      }
#pragma unroll
      for (int i = 0; i < 4; ++i)
#pragma unroll
        for (int j = 0; j < 4; ++j)
          acc[i][j] = __builtin_amdgcn_mfma_f32_16x16x32_bf16(af[i], bf[j], acc[i][j], 0, 0, 0);
    }
  };

  const int nk = KDIM / BK;
  LOADS(0);
  DSWRITE(0);
  __syncthreads();
  int cur = 0;
  for (int t = 0; t < nk; ++t){
    const bool more = (t + 1 < nk);
    if (more) LOADS(t + 1);       // issue early (T14)
    COMPUTE(cur);                 // hide load latency under MFMA
    if (more){
      DSWRITE(cur ^ 1);           // write late, other buffer
      __syncthreads();
    }
    cur ^= 1;
  }

  if (PHASE == 1){
#pragma unroll
    for (int j = 0; j < 4; ++j){
      const int n = n0 + wc * 64 + j * 16 + (lane & 15);
      const float bv = bias[(size_t)e * NDIM + n];
#pragma unroll
      for (int i = 0; i < 4; ++i){
#pragma unroll
        for (int q = 0; q < 4; ++q){
          int lm = wr * 64 + i * 16 + (lane >> 4) * 4 + q;
          if (lm < mrows){
            float v = acc[i][j][q] + bv;
            v = 0.5f * v * (1.0f + erff(v * 0.70710678118654752f));  // exact GELU
            Hout[(size_t)(off + m0 + lm) * NDIM + n] = (short)f2bf(v);
          }
        }
      }
    }
  } else {
#pragma unroll
    for (int j = 0; j < 4; ++j){
      const int n = n0 + wc * 64 + j * 16 + (lane & 15);
#pragma unroll
      for (int i = 0; i < 4; ++i){
#pragma unroll
        for (int q = 0; q < 4; ++q){
          int lm = wr * 64 + i * 16 + (lane >> 4) * 4 + q;
          if (lm < mrows){
            int p = off + m0 + lm;
            int tok = tokp[p];
            float w = wtp[p];
            atomicAdd(&Out[(size_t)tok * NDIM + n], w * acc[i][j][q]);
          }
        }
      }
    }
  }
}

extern "C" void kernel_launch(void* const* d_in, const int* in_sizes, int n_in,
                              void* d_out, int out_size, void* d_ws, size_t ws_size,
                              hipStream_t stream){
  const float* x  = (const float*)d_in[0];
  const float* gw = (const float*)d_in[1];
  const float* gb = (const float*)d_in[2];
  const float* w1 = (const float*)d_in[3];
  const float* b1 = (const float*)d_in[4];
  const float* w2 = (const float*)d_in[5];
  const float* b2 = (const float*)d_in[6];
  float* outF = (float*)d_out;

  char* p = (char*)d_ws;
  short* xb   = (short*)p;  p += (size_t)NTOK * DDIM * 2;        // 8.4 MB
  short* h    = (short*)p;  p += (size_t)NTOK * 2 * HDIM * 2;    // 67 MB
  int*   tokp = (int*)p;    p += (size_t)NTOK * 2 * 4;
  float* wtp  = (float*)p;  p += (size_t)NTOK * 2 * 4;
  int2*  te   = (int2*)p;   p += (size_t)NTOK * 8;
  float2* tw  = (float2*)p; p += (size_t)NTOK * 8;
  int* meta = (int*)p;      // cnt[8] | offs[8] | cur[8]
  int* cnt  = meta;
  int* offs = meta + 8;
  int* cur  = meta + 16;

  hipMemsetAsync(meta, 0, 24 * sizeof(int), stream);
  convert_x_kernel<<<2048, 256, 0, stream>>>(x, xb);
  gate_kernel<<<NTOK, 64, 0, stream>>>(x, gw, gb, outF, te, tw, cnt);
  scan_kernel<<<1, 64, 0, stream>>>(cnt, offs);
  scatter_kernel<<<(NTOK + 255) / 256, 256, 0, stream>>>(te, tw, offs, cur, tokp, wtp);
  out_init_kernel<<<NTOK, 256, 0, stream>>>(te, tw, b2, outF);
  moe_gemm<1, DDIM, HDIM><<<dim3(HDIM / BN, NTOK / BM, EEXP), 256, 0, stream>>>(
      xb, w1, b1, cnt, offs, tokp, wtp, h, nullptr);
  moe_gemm<2, HDIM, DDIM><<<dim3(DDIM / BN, NTOK / BM, EEXP), 256, 0, stream>>>(
      h, w2, nullptr, cnt, offs, tokp, wtp, nullptr, outF);
}